// Round 12
// baseline (209.542 us; speedup 1.0000x reference)
//
#include <hip/hip_runtime.h>
#include <hip/hip_bf16.h>

// Problem dims (fixed by reference): B=2,S=1024 -> T=2048 tokens
#define T_TOK 2048
#define DIM   2048   // D
#define FFN   1024   // F
#define NE    8      // experts
// top_k = 2 hardcoded

typedef __attribute__((ext_vector_type(8))) short bf16x8;
typedef __attribute__((ext_vector_type(4))) float f32x4;

__device__ __forceinline__ unsigned short f2bf(float f) {
  __hip_bfloat16 h = __float2bfloat16(f);
  return __builtin_bit_cast(unsigned short, h);
}

__device__ __forceinline__ void gload_lds16(const unsigned short* g, unsigned short* l) {
  __builtin_amdgcn_global_load_lds(
      (const __attribute__((address_space(1))) void*)g,
      (__attribute__((address_space(3))) void*)l, 16, 0, 0);
}

// ---------------- zero d_out ----------------
__global__ void zero_out(float4* __restrict__ o, int n4) {
  int i = blockIdx.x * blockDim.x + threadIdx.x;
  int stride = gridDim.x * blockDim.x;
  float4 z = {0.f, 0.f, 0.f, 0.f};
  for (; i < n4; i += stride) o[i] = z;
}

// ---------------- fp32 -> bf16 weights: NON-TEMPORAL fp32 loads (R11-frozen) ----------------
__global__ __launch_bounds__(256) void cvt_w(
    const float* __restrict__ wg, const float* __restrict__ wu, const float* __restrict__ wd,
    unsigned short* __restrict__ wgb, unsigned short* __restrict__ wub,
    unsigned short* __restrict__ wdb) {
  int b = blockIdx.x;
  const float* src; unsigned short* dst;
  if (b < 2048)       { src = wg; dst = wgb; }
  else if (b < 4096)  { src = wu; dst = wub; b -= 2048; }
  else                { src = wd; dst = wdb; b -= 4096; }
  const f32x4* s = reinterpret_cast<const f32x4*>(src) + (long)b * 2048 + threadIdx.x;
  ushort4* d = reinterpret_cast<ushort4*>(dst) + (long)b * 2048 + threadIdx.x;
  f32x4 v[8];
#pragma unroll
  for (int g = 0; g < 8; ++g) v[g] = __builtin_nontemporal_load(&s[g * 256]);
#pragma unroll
  for (int g = 0; g < 8; ++g) {
    ushort4 o;
    o.x = f2bf(v[g][0]); o.y = f2bf(v[g][1]); o.z = f2bf(v[g][2]); o.w = f2bf(v[g][3]);
    d[g * 256] = o;
  }
}

// ---------------- router: logits + top2 + softmax gates, + emits bf16 x ----------------
__global__ __launch_bounds__(256) void router_topk(
    const float* __restrict__ x, const float* __restrict__ wr,
    int* __restrict__ top_i, float* __restrict__ top_g,
    unsigned short* __restrict__ xb) {
  int t = blockIdx.x * 4 + (threadIdx.x >> 6);
  int lane = threadIdx.x & 63;
  const float4* xr = reinterpret_cast<const float4*>(x) + (size_t)t * (DIM / 4);
  const float4* wrv = reinterpret_cast<const float4*>(wr);
  ushort4* xbr = reinterpret_cast<ushort4*>(xb + (size_t)t * DIM);
  float acc[NE];
#pragma unroll
  for (int e = 0; e < NE; ++e) acc[e] = 0.f;
#pragma unroll
  for (int it = 0; it < DIM / 4 / 64; ++it) {
    int d4 = it * 64 + lane;
    float4 xv = xr[d4];
    ushort4 o;
    o.x = f2bf(xv.x); o.y = f2bf(xv.y); o.z = f2bf(xv.z); o.w = f2bf(xv.w);
    xbr[d4] = o;
#pragma unroll
    for (int e = 0; e < NE; ++e) {
      float4 wv = wrv[e * (DIM / 4) + d4];
      acc[e] += xv.x * wv.x + xv.y * wv.y + xv.z * wv.z + xv.w * wv.w;
    }
  }
#pragma unroll
  for (int off = 32; off > 0; off >>= 1) {
#pragma unroll
    for (int e = 0; e < NE; ++e) acc[e] += __shfl_xor(acc[e], off, 64);
  }
  if (lane == 0) {
    int i0 = 0; float m0 = acc[0];
#pragma unroll
    for (int e = 1; e < NE; ++e) if (acc[e] > m0) { m0 = acc[e]; i0 = e; }
    int i1 = -1; float m1 = -3.4e38f;
#pragma unroll
    for (int e = 0; e < NE; ++e) if (e != i0 && acc[e] > m1) { m1 = acc[e]; i1 = e; }
    float tv = expf(m1 - m0);
    float den = 1.f + tv;
    top_i[t * 2 + 0] = i0; top_i[t * 2 + 1] = i1;
    top_g[t * 2 + 0] = 1.f / den; top_g[t * 2 + 1] = tv / den;
  }
}

// ---------------- count per expert + exclusive prefix offsets ----------------
__global__ void count_offsets(const int* __restrict__ top_i,
                              int* __restrict__ offs, int* __restrict__ cursor) {
  __shared__ int cnt[NE];
  if (threadIdx.x < NE) cnt[threadIdx.x] = 0;
  __syncthreads();
  for (int i = threadIdx.x; i < T_TOK * 2; i += blockDim.x) atomicAdd(&cnt[top_i[i]], 1);
  __syncthreads();
  if (threadIdx.x == 0) {
    int s = 0;
    for (int e = 0; e < NE; ++e) { offs[e] = s; cursor[e] = s; s += cnt[e]; }
    offs[NE] = s;
  }
}

// ---------------- scatter tokens into compact per-expert lists ----------------
__global__ void scatter_tokens(const int* __restrict__ top_i, const float* __restrict__ top_g,
                               int* __restrict__ cursor, int* __restrict__ tok_list,
                               float* __restrict__ gate_lst) {
  int t = blockIdx.x * blockDim.x + threadIdx.x;
  if (t >= T_TOK) return;
#pragma unroll
  for (int s = 0; s < 2; ++s) {
    int e = top_i[t * 2 + s];
    int p = atomicAdd(&cursor[e], 1);
    tok_list[p] = t;
    gate_lst[p] = top_g[t * 2 + s];
  }
}

// ============ fused gate+up grouped GEMM: BM=64, BN=64, BK=64, T3-min dbuf ============
// R11 tile/swizzle/epilogue frozen; loop restructured: stage(next) -> compute(cur) ->
// single barrier (implicit vmcnt(0) drain). Loads get the whole MFMA phase to land.
__global__ __launch_bounds__(256, 3) void gateup_gemm(
    const unsigned short* __restrict__ xb, const unsigned short* __restrict__ wgb,
    const unsigned short* __restrict__ wub, const int* __restrict__ tok_list,
    const int* __restrict__ offs, unsigned short* __restrict__ hbuf) {
  const int e = blockIdx.z;
  const int row0 = offs[e];
  const int n_e = offs[e + 1] - row0;
  const int mt = blockIdx.y;
  if (mt * 64 >= n_e) return;
  const int nt = blockIdx.x;    // F tile of 64

  __shared__ unsigned short As[2][64 * 64];   // 2 x 8KB
  __shared__ unsigned short Bg[2][64 * 64];   // 2 x 8KB
  __shared__ unsigned short Bu[2][64 * 64];   // 2 x 8KB

  const int tid = threadIdx.x;
  const int wid = tid >> 6;
  const int lane = tid & 63;

  const int gchunk = (((lane & 7) ^ ((lane >> 3) & 7)) << 3);

  const unsigned short* gA[2];
  int lAoff[2];
#pragma unroll
  for (int p = 0; p < 2; ++p) {
    int rt = wid * 16 + p * 8 + (lane >> 3);
    int ar = mt * 64 + rt; if (ar >= n_e) ar = n_e - 1;
    gA[p] = xb + (size_t)tok_list[row0 + ar] * DIM + gchunk;
    lAoff[p] = (wid * 16 + p * 8) * 64;
  }
  const size_t wbase = (size_t)e * FFN * DIM + (size_t)(nt * 64) * DIM;
  const unsigned short* gG[2];
  const unsigned short* gU[2];
  int lBoff[2];
#pragma unroll
  for (int p = 0; p < 2; ++p) {
    int rt = wid * 16 + p * 8 + (lane >> 3);
    gG[p] = wgb + wbase + (size_t)rt * DIM + gchunk;
    gU[p] = wub + wbase + (size_t)rt * DIM + gchunk;
    lBoff[p] = (wid * 16 + p * 8) * 64;
  }

  auto stage = [&](int buf, int k0) {
#pragma unroll
    for (int p = 0; p < 2; ++p) {
      gload_lds16(gA[p] + k0, &As[buf][lAoff[p]]);
      gload_lds16(gG[p] + k0, &Bg[buf][lBoff[p]]);
      gload_lds16(gU[p] + k0, &Bu[buf][lBoff[p]]);
    }
  };

  f32x4 accg[2][2];
  f32x4 accu[2][2];
#pragma unroll
  for (int i = 0; i < 2; ++i)
#pragma unroll
    for (int j = 0; j < 2; ++j) {
      accg[i][j] = (f32x4){0.f, 0.f, 0.f, 0.f};
      accu[i][j] = (f32x4){0.f, 0.f, 0.f, 0.f};
    }

  const int warow = (wid >> 1) * 32;   // 2x2 wave grid, 32x32 per wave
  const int wacol = (wid & 1) * 32;
  const int frow = lane & 15;
  const int eo0 = ((((lane >> 4)) ^ (lane & 7)) << 3);
  const int eo1 = (((4 + (lane >> 4)) ^ (lane & 7)) << 3);

  stage(0, 0);
  __syncthreads();

  const int NT = DIM / 64;
  int cur = 0;
  for (int t = 0; t < NT; ++t) {
    if (t + 1 < NT) stage(cur ^ 1, (t + 1) * 64);
#pragma unroll
    for (int kk = 0; kk < 2; ++kk) {
      const int eo = kk ? eo1 : eo0;
      bf16x8 af[2], bg[2], bu[2];
#pragma unroll
      for (int i = 0; i < 2; ++i)
        af[i] = *reinterpret_cast<const bf16x8*>(&As[cur][(warow + i * 16 + frow) * 64 + eo]);
#pragma unroll
      for (int j = 0; j < 2; ++j) {
        bg[j] = *reinterpret_cast<const bf16x8*>(&Bg[cur][(wacol + j * 16 + frow) * 64 + eo]);
        bu[j] = *reinterpret_cast<const bf16x8*>(&Bu[cur][(wacol + j * 16 + frow) * 64 + eo]);
      }
#pragma unroll
      for (int i = 0; i < 2; ++i)
#pragma unroll
        for (int j = 0; j < 2; ++j) {
          accg[i][j] = __builtin_amdgcn_mfma_f32_16x16x32_bf16(af[i], bg[j], accg[i][j], 0, 0, 0);
          accu[i][j] = __builtin_amdgcn_mfma_f32_16x16x32_bf16(af[i], bu[j], accu[i][j], 0, 0, 0);
        }
    }
    __syncthreads();
    cur ^= 1;
  }

  // epilogue: h = silu(g)*u -> bf16
#pragma unroll
  for (int i = 0; i < 2; ++i) {
#pragma unroll
    for (int jj = 0; jj < 4; ++jj) {
      int r = mt * 64 + warow + i * 16 + (lane >> 4) * 4 + jj;
      if (r < n_e) {
#pragma unroll
        for (int j = 0; j < 2; ++j) {
          float g = accg[i][j][jj];
          float u = accu[i][j][jj];
          float h = (g / (1.f + __expf(-g))) * u;
          int f = nt * 64 + wacol + j * 16 + (lane & 15);
          hbuf[(size_t)(row0 + r) * FFN + f] = f2bf(h);
        }
      }
    }
  }
}

// ============ grouped down GEMM: BM=64, BN=128, BK=64, T3-min dbuf ============
// Epilogue: atomicAdd into out (exactly 2 commutative fp32 adds/element -> deterministic).
__global__ __launch_bounds__(256, 3) void down_gemm(
    const unsigned short* __restrict__ hbuf, const unsigned short* __restrict__ wdb,
    const int* __restrict__ tok_list, const float* __restrict__ gate_lst,
    const int* __restrict__ offs, float* __restrict__ out) {
  const int e = blockIdx.z;
  const int row0 = offs[e];
  const int n_e = offs[e + 1] - row0;
  const int mt = blockIdx.y;
  if (mt * 64 >= n_e) return;
  const int nt = blockIdx.x;  // D tile

  __shared__ unsigned short As[2][64 * 64];    // 2 x 8KB
  __shared__ unsigned short Bs[2][128 * 64];   // 2 x 16KB

  const int tid = threadIdx.x;
  const int wid = tid >> 6;
  const int lane = tid & 63;

  const int gchunk = (((lane & 7) ^ ((lane >> 3) & 7)) << 3);

  const unsigned short* gA[2];
  int lAoff[2];
#pragma unroll
  for (int p = 0; p < 2; ++p) {
    int rt = wid * 16 + p * 8 + (lane >> 3);
    int ar = mt * 64 + rt; if (ar >= n_e) ar = n_e - 1;
    gA[p] = hbuf + (size_t)(row0 + ar) * FFN + gchunk;
    lAoff[p] = (wid * 16 + p * 8) * 64;
  }
  const unsigned short* gB[4];
  int lBoff[4];
#pragma unroll
  for (int p = 0; p < 4; ++p) {
    int rt = wid * 32 + p * 8 + (lane >> 3);
    gB[p] = wdb + ((size_t)e * DIM + nt * 128 + rt) * FFN + gchunk;
    lBoff[p] = (wid * 32 + p * 8) * 64;
  }

  auto stage = [&](int buf, int k0) {
#pragma unroll
    for (int p = 0; p < 2; ++p) gload_lds16(gA[p] + k0, &As[buf][lAoff[p]]);
#pragma unroll
    for (int p = 0; p < 4; ++p) gload_lds16(gB[p] + k0, &Bs[buf][lBoff[p]]);
  };

  f32x4 acc[2][4];
#pragma unroll
  for (int i = 0; i < 2; ++i)
#pragma unroll
    for (int j = 0; j < 4; ++j) acc[i][j] = (f32x4){0.f, 0.f, 0.f, 0.f};

  const int warow = (wid >> 1) * 32;
  const int wacol = (wid & 1) * 64;
  const int frow = lane & 15;
  const int eo0 = ((((lane >> 4)) ^ (lane & 7)) << 3);
  const int eo1 = (((4 + (lane >> 4)) ^ (lane & 7)) << 3);

  stage(0, 0);
  __syncthreads();

  const int NT = FFN / 64;
  int cur = 0;
  for (int t = 0; t < NT; ++t) {
    if (t + 1 < NT) stage(cur ^ 1, (t + 1) * 64);
#pragma unroll
    for (int kk = 0; kk < 2; ++kk) {
      const int eo = kk ? eo1 : eo0;
      bf16x8 af[2], bf[4];
#pragma unroll
      for (int i = 0; i < 2; ++i)
        af[i] = *reinterpret_cast<const bf16x8*>(&As[cur][(warow + i * 16 + frow) * 64 + eo]);
#pragma unroll
      for (int j = 0; j < 4; ++j)
        bf[j] = *reinterpret_cast<const bf16x8*>(&Bs[cur][(wacol + j * 16 + frow) * 64 + eo]);
#pragma unroll
      for (int i = 0; i < 2; ++i)
#pragma unroll
        for (int j = 0; j < 4; ++j)
          acc[i][j] = __builtin_amdgcn_mfma_f32_16x16x32_bf16(af[i], bf[j], acc[i][j], 0, 0, 0);
    }
    __syncthreads();
    cur ^= 1;
  }

#pragma unroll
  for (int i = 0; i < 2; ++i) {
#pragma unroll
    for (int jj = 0; jj < 4; ++jj) {
      int r = mt * 64 + warow + i * 16 + (lane >> 4) * 4 + jj;
      if (r < n_e) {
        int tk = tok_list[row0 + r];
        float gt = gate_lst[row0 + r];
        float* yrow = out + (size_t)tk * DIM;
#pragma unroll
        for (int j = 0; j < 4; ++j) {
          int d = nt * 128 + wacol + j * 16 + (lane & 15);
          atomicAdd(&yrow[d], gt * acc[i][j][jj]);
        }
      }
    }
  }
}

extern "C" void kernel_launch(void* const* d_in, const int* in_sizes, int n_in,
                              void* d_out, int out_size, void* d_ws, size_t ws_size,
                              hipStream_t stream) {
  const float* x = (const float*)d_in[0];
  const float* wr = (const float*)d_in[1];
  const float* wg = (const float*)d_in[2];
  const float* wu = (const float*)d_in[3];
  const float* wd = (const float*)d_in[4];
  float* out = (float*)d_out;

  char* ws = (char*)d_ws;
  size_t off = 0;
  auto alloc = [&](size_t bytes) {
    char* p = ws + off;
    off += (bytes + 255) & ~(size_t)255;
    return p;
  };
  unsigned short* xb   = (unsigned short*)alloc((size_t)T_TOK * DIM * 2);
  unsigned short* wgb  = (unsigned short*)alloc((size_t)NE * FFN * DIM * 2);
  unsigned short* wub  = (unsigned short*)alloc((size_t)NE * FFN * DIM * 2);
  unsigned short* wdb  = (unsigned short*)alloc((size_t)NE * DIM * FFN * 2);
  unsigned short* hbuf = (unsigned short*)alloc((size_t)T_TOK * 2 * FFN * 2);
  int* top_i     = (int*)alloc(T_TOK * 2 * 4);
  float* top_g   = (float*)alloc(T_TOK * 2 * 4);
  int* tok_list  = (int*)alloc(T_TOK * 2 * 4);
  float* gate_lst = (float*)alloc(T_TOK * 2 * 4);
  int* offs      = (int*)alloc(64);
  int* cursor    = (int*)alloc(64);
  if (off > ws_size) return;

  zero_out<<<1024, 256, 0, stream>>>((float4*)out, T_TOK * DIM / 4);
  cvt_w<<<6144, 256, 0, stream>>>(wg, wu, wd, wgb, wub, wdb);
  router_topk<<<T_TOK / 4, 256, 0, stream>>>(x, wr, top_i, top_g, xb);
  count_offsets<<<1, 256, 0, stream>>>(top_i, offs, cursor);
  scatter_tokens<<<(T_TOK + 255) / 256, 256, 0, stream>>>(top_i, top_g, cursor, tok_list,
                                                          gate_lst);
  gateup_gemm<<<dim3(FFN / 64, 32, NE), 256, 0, stream>>>(xb, wgb, wub, tok_list, offs, hbuf);
  down_gemm<<<dim3(DIM / 128, 32, NE), 256, 0, stream>>>(hbuf, wdb, tok_list, gate_lst,
                                                         offs, out);
}

// Round 13
// 192.651 us; speedup vs baseline: 1.0877x; 1.0877x over previous
//
#include <hip/hip_runtime.h>
#include <hip/hip_bf16.h>

// Problem dims (fixed by reference): B=2,S=1024 -> T=2048 tokens
#define T_TOK 2048
#define DIM   2048   // D
#define FFN   1024   // F
#define NE    8      // experts
// top_k = 2 hardcoded

typedef __attribute__((ext_vector_type(8))) short bf16x8;
typedef __attribute__((ext_vector_type(4))) float f32x4;

__device__ __forceinline__ unsigned short f2bf(float f) {
  __hip_bfloat16 h = __float2bfloat16(f);
  return __builtin_bit_cast(unsigned short, h);
}

__device__ __forceinline__ void gload_lds16(const unsigned short* g, unsigned short* l) {
  __builtin_amdgcn_global_load_lds(
      (const __attribute__((address_space(1))) void*)g,
      (__attribute__((address_space(3))) void*)l, 16, 0, 0);
}

// ============ fused preprocessing: cvt_w (nt) + router(+cvt x, nt) + zero_out ============
// blocks [0,6144): weight fp32->bf16, nontemporal loads (R11-proven)
// blocks [6144,6656): router top-2 + softmax gates + bf16 x emission
// blocks [6656,6912): zero d_out
__global__ __launch_bounds__(256) void prep(
    const float* __restrict__ x, const float* __restrict__ wr,
    const float* __restrict__ wg, const float* __restrict__ wu, const float* __restrict__ wd,
    unsigned short* __restrict__ xb, unsigned short* __restrict__ wgb,
    unsigned short* __restrict__ wub, unsigned short* __restrict__ wdb,
    int* __restrict__ top_i, float* __restrict__ top_g, float4* __restrict__ outz) {
  const int bid = blockIdx.x;
  if (bid < 6144) {
    int b = bid;
    const float* src; unsigned short* dst;
    if (b < 2048)       { src = wg; dst = wgb; }
    else if (b < 4096)  { src = wu; dst = wub; b -= 2048; }
    else                { src = wd; dst = wdb; b -= 4096; }
    const f32x4* s = reinterpret_cast<const f32x4*>(src) + (long)b * 2048 + threadIdx.x;
    ushort4* d = reinterpret_cast<ushort4*>(dst) + (long)b * 2048 + threadIdx.x;
    f32x4 v[8];
#pragma unroll
    for (int g = 0; g < 8; ++g) v[g] = __builtin_nontemporal_load(&s[g * 256]);
#pragma unroll
    for (int g = 0; g < 8; ++g) {
      ushort4 o;
      o.x = f2bf(v[g][0]); o.y = f2bf(v[g][1]); o.z = f2bf(v[g][2]); o.w = f2bf(v[g][3]);
      d[g * 256] = o;
    }
    return;
  }
  if (bid < 6656) {
    int t = (bid - 6144) * 4 + (threadIdx.x >> 6);
    int lane = threadIdx.x & 63;
    const f32x4* xr = reinterpret_cast<const f32x4*>(x) + (size_t)t * (DIM / 4);
    const float4* wrv = reinterpret_cast<const float4*>(wr);
    ushort4* xbr = reinterpret_cast<ushort4*>(xb + (size_t)t * DIM);
    float acc[NE];
#pragma unroll
    for (int e = 0; e < NE; ++e) acc[e] = 0.f;
#pragma unroll
    for (int it = 0; it < DIM / 4 / 64; ++it) {
      int d4 = it * 64 + lane;
      f32x4 xv = __builtin_nontemporal_load(&xr[d4]);
      ushort4 o;
      o.x = f2bf(xv[0]); o.y = f2bf(xv[1]); o.z = f2bf(xv[2]); o.w = f2bf(xv[3]);
      xbr[d4] = o;
#pragma unroll
      for (int e = 0; e < NE; ++e) {
        float4 wv = wrv[e * (DIM / 4) + d4];
        acc[e] += xv[0] * wv.x + xv[1] * wv.y + xv[2] * wv.z + xv[3] * wv.w;
      }
    }
#pragma unroll
    for (int off = 32; off > 0; off >>= 1) {
#pragma unroll
      for (int e = 0; e < NE; ++e) acc[e] += __shfl_xor(acc[e], off, 64);
    }
    if (lane == 0) {
      int i0 = 0; float m0 = acc[0];
#pragma unroll
      for (int e = 1; e < NE; ++e) if (acc[e] > m0) { m0 = acc[e]; i0 = e; }
      int i1 = -1; float m1 = -3.4e38f;
#pragma unroll
      for (int e = 0; e < NE; ++e) if (e != i0 && acc[e] > m1) { m1 = acc[e]; i1 = e; }
      float tv = expf(m1 - m0);
      float den = 1.f + tv;
      top_i[t * 2 + 0] = i0; top_i[t * 2 + 1] = i1;
      top_g[t * 2 + 0] = 1.f / den; top_g[t * 2 + 1] = tv / den;
    }
    return;
  }
  // zero d_out: 256 blocks cover 2^20 float4
  int i = (bid - 6656) * 256 + threadIdx.x;
  float4 z = {0.f, 0.f, 0.f, 0.f};
  for (; i < T_TOK * DIM / 4; i += 256 * 256) outz[i] = z;
}

// ---------------- count per expert + exclusive prefix offsets ----------------
__global__ void count_offsets(const int* __restrict__ top_i,
                              int* __restrict__ offs, int* __restrict__ cursor) {
  __shared__ int cnt[NE];
  if (threadIdx.x < NE) cnt[threadIdx.x] = 0;
  __syncthreads();
  for (int i = threadIdx.x; i < T_TOK * 2; i += blockDim.x) atomicAdd(&cnt[top_i[i]], 1);
  __syncthreads();
  if (threadIdx.x == 0) {
    int s = 0;
    for (int e = 0; e < NE; ++e) { offs[e] = s; cursor[e] = s; s += cnt[e]; }
    offs[NE] = s;
  }
}

// ---------------- scatter tokens into compact per-expert lists ----------------
__global__ void scatter_tokens(const int* __restrict__ top_i, const float* __restrict__ top_g,
                               int* __restrict__ cursor, int* __restrict__ tok_list,
                               float* __restrict__ gate_lst) {
  int t = blockIdx.x * blockDim.x + threadIdx.x;
  if (t >= T_TOK) return;
#pragma unroll
  for (int s = 0; s < 2; ++s) {
    int e = top_i[t * 2 + s];
    int p = atomicAdd(&cursor[e], 1);
    tok_list[p] = t;
    gate_lst[p] = top_g[t * 2 + s];
  }
}

// ============ fused gate+up grouped GEMM: BM=64, BN=64, BK=64, T4 counted-vmcnt dbuf ============
// Per iter: stage(next tile, 6 loads/wave) -> s_waitcnt vmcnt(6) (prev tile landed,
// next still in flight) -> s_barrier -> compute -> s_barrier (buffer write-protect).
// Loads get a full iteration of slack instead of draining at each barrier.
__global__ __launch_bounds__(256, 3) void gateup_gemm(
    const unsigned short* __restrict__ xb, const unsigned short* __restrict__ wgb,
    const unsigned short* __restrict__ wub, const int* __restrict__ tok_list,
    const int* __restrict__ offs, unsigned short* __restrict__ hbuf) {
  const int e = blockIdx.z;
  const int row0 = offs[e];
  const int n_e = offs[e + 1] - row0;
  const int mt = blockIdx.y;
  if (mt * 64 >= n_e) return;
  const int nt = blockIdx.x;    // F tile of 64

  __shared__ unsigned short As[2][64 * 64];   // 2 x 8KB
  __shared__ unsigned short Bg[2][64 * 64];   // 2 x 8KB
  __shared__ unsigned short Bu[2][64 * 64];   // 2 x 8KB

  const int tid = threadIdx.x;
  const int wid = tid >> 6;
  const int lane = tid & 63;

  const int gchunk = (((lane & 7) ^ ((lane >> 3) & 7)) << 3);

  const unsigned short* gA[2];
  int lAoff[2];
#pragma unroll
  for (int p = 0; p < 2; ++p) {
    int rt = wid * 16 + p * 8 + (lane >> 3);
    int ar = mt * 64 + rt; if (ar >= n_e) ar = n_e - 1;
    gA[p] = xb + (size_t)tok_list[row0 + ar] * DIM + gchunk;
    lAoff[p] = (wid * 16 + p * 8) * 64;
  }
  const size_t wbase = (size_t)e * FFN * DIM + (size_t)(nt * 64) * DIM;
  const unsigned short* gG[2];
  const unsigned short* gU[2];
  int lBoff[2];
#pragma unroll
  for (int p = 0; p < 2; ++p) {
    int rt = wid * 16 + p * 8 + (lane >> 3);
    gG[p] = wgb + wbase + (size_t)rt * DIM + gchunk;
    gU[p] = wub + wbase + (size_t)rt * DIM + gchunk;
    lBoff[p] = (wid * 16 + p * 8) * 64;
  }

  auto stage = [&](int buf, int k0) {   // 6 gload_lds per wave
#pragma unroll
    for (int p = 0; p < 2; ++p) {
      gload_lds16(gA[p] + k0, &As[buf][lAoff[p]]);
      gload_lds16(gG[p] + k0, &Bg[buf][lBoff[p]]);
      gload_lds16(gU[p] + k0, &Bu[buf][lBoff[p]]);
    }
  };

  f32x4 accg[2][2];
  f32x4 accu[2][2];
#pragma unroll
  for (int i = 0; i < 2; ++i)
#pragma unroll
    for (int j = 0; j < 2; ++j) {
      accg[i][j] = (f32x4){0.f, 0.f, 0.f, 0.f};
      accu[i][j] = (f32x4){0.f, 0.f, 0.f, 0.f};
    }

  const int warow = (wid >> 1) * 32;   // 2x2 wave grid, 32x32 per wave
  const int wacol = (wid & 1) * 32;
  const int frow = lane & 15;
  const int eo0 = ((((lane >> 4)) ^ (lane & 7)) << 3);
  const int eo1 = (((4 + (lane >> 4)) ^ (lane & 7)) << 3);

  stage(0, 0);

  const int NT = DIM / 64;
  int cur = 0;
  for (int t = 0; t < NT; ++t) {
    if (t + 1 < NT) {
      stage(cur ^ 1, (t + 1) * 64);
      asm volatile("s_waitcnt vmcnt(6)" ::: "memory");
    } else {
      asm volatile("s_waitcnt vmcnt(0)" ::: "memory");
    }
    __builtin_amdgcn_sched_barrier(0);
    __builtin_amdgcn_s_barrier();
    __builtin_amdgcn_sched_barrier(0);
#pragma unroll
    for (int kk = 0; kk < 2; ++kk) {
      const int eo = kk ? eo1 : eo0;
      bf16x8 af[2], bg[2], bu[2];
#pragma unroll
      for (int i = 0; i < 2; ++i)
        af[i] = *reinterpret_cast<const bf16x8*>(&As[cur][(warow + i * 16 + frow) * 64 + eo]);
#pragma unroll
      for (int j = 0; j < 2; ++j) {
        bg[j] = *reinterpret_cast<const bf16x8*>(&Bg[cur][(wacol + j * 16 + frow) * 64 + eo]);
        bu[j] = *reinterpret_cast<const bf16x8*>(&Bu[cur][(wacol + j * 16 + frow) * 64 + eo]);
      }
#pragma unroll
      for (int i = 0; i < 2; ++i)
#pragma unroll
        for (int j = 0; j < 2; ++j) {
          accg[i][j] = __builtin_amdgcn_mfma_f32_16x16x32_bf16(af[i], bg[j], accg[i][j], 0, 0, 0);
          accu[i][j] = __builtin_amdgcn_mfma_f32_16x16x32_bf16(af[i], bu[j], accu[i][j], 0, 0, 0);
        }
    }
    __builtin_amdgcn_sched_barrier(0);
    __builtin_amdgcn_s_barrier();
    __builtin_amdgcn_sched_barrier(0);
    cur ^= 1;
  }

  // epilogue: h = silu(g)*u -> bf16
#pragma unroll
  for (int i = 0; i < 2; ++i) {
#pragma unroll
    for (int jj = 0; jj < 4; ++jj) {
      int r = mt * 64 + warow + i * 16 + (lane >> 4) * 4 + jj;
      if (r < n_e) {
#pragma unroll
        for (int j = 0; j < 2; ++j) {
          float g = accg[i][j][jj];
          float u = accu[i][j][jj];
          float h = (g / (1.f + __expf(-g))) * u;
          int f = nt * 64 + wacol + j * 16 + (lane & 15);
          hbuf[(size_t)(row0 + r) * FFN + f] = f2bf(h);
        }
      }
    }
  }
}

// ============ grouped down GEMM: BM=64, BN=128, BK=64, T4 counted-vmcnt dbuf ============
// Epilogue: atomicAdd into out (exactly 2 commutative fp32 adds/element -> deterministic).
__global__ __launch_bounds__(256, 3) void down_gemm(
    const unsigned short* __restrict__ hbuf, const unsigned short* __restrict__ wdb,
    const int* __restrict__ tok_list, const float* __restrict__ gate_lst,
    const int* __restrict__ offs, float* __restrict__ out) {
  const int e = blockIdx.z;
  const int row0 = offs[e];
  const int n_e = offs[e + 1] - row0;
  const int mt = blockIdx.y;
  if (mt * 64 >= n_e) return;
  const int nt = blockIdx.x;  // D tile

  __shared__ unsigned short As[2][64 * 64];    // 2 x 8KB
  __shared__ unsigned short Bs[2][128 * 64];   // 2 x 16KB

  const int tid = threadIdx.x;
  const int wid = tid >> 6;
  const int lane = tid & 63;

  const int gchunk = (((lane & 7) ^ ((lane >> 3) & 7)) << 3);

  const unsigned short* gA[2];
  int lAoff[2];
#pragma unroll
  for (int p = 0; p < 2; ++p) {
    int rt = wid * 16 + p * 8 + (lane >> 3);
    int ar = mt * 64 + rt; if (ar >= n_e) ar = n_e - 1;
    gA[p] = hbuf + (size_t)(row0 + ar) * FFN + gchunk;
    lAoff[p] = (wid * 16 + p * 8) * 64;
  }
  const unsigned short* gB[4];
  int lBoff[4];
#pragma unroll
  for (int p = 0; p < 4; ++p) {
    int rt = wid * 32 + p * 8 + (lane >> 3);
    gB[p] = wdb + ((size_t)e * DIM + nt * 128 + rt) * FFN + gchunk;
    lBoff[p] = (wid * 32 + p * 8) * 64;
  }

  auto stage = [&](int buf, int k0) {   // 6 gload_lds per wave
#pragma unroll
    for (int p = 0; p < 2; ++p) gload_lds16(gA[p] + k0, &As[buf][lAoff[p]]);
#pragma unroll
    for (int p = 0; p < 4; ++p) gload_lds16(gB[p] + k0, &Bs[buf][lBoff[p]]);
  };

  f32x4 acc[2][4];
#pragma unroll
  for (int i = 0; i < 2; ++i)
#pragma unroll
    for (int j = 0; j < 4; ++j) acc[i][j] = (f32x4){0.f, 0.f, 0.f, 0.f};

  const int warow = (wid >> 1) * 32;
  const int wacol = (wid & 1) * 64;
  const int frow = lane & 15;
  const int eo0 = ((((lane >> 4)) ^ (lane & 7)) << 3);
  const int eo1 = (((4 + (lane >> 4)) ^ (lane & 7)) << 3);

  stage(0, 0);

  const int NT = FFN / 64;
  int cur = 0;
  for (int t = 0; t < NT; ++t) {
    if (t + 1 < NT) {
      stage(cur ^ 1, (t + 1) * 64);
      asm volatile("s_waitcnt vmcnt(6)" ::: "memory");
    } else {
      asm volatile("s_waitcnt vmcnt(0)" ::: "memory");
    }
    __builtin_amdgcn_sched_barrier(0);
    __builtin_amdgcn_s_barrier();
    __builtin_amdgcn_sched_barrier(0);
#pragma unroll
    for (int kk = 0; kk < 2; ++kk) {
      const int eo = kk ? eo1 : eo0;
      bf16x8 af[2], bf[4];
#pragma unroll
      for (int i = 0; i < 2; ++i)
        af[i] = *reinterpret_cast<const bf16x8*>(&As[cur][(warow + i * 16 + frow) * 64 + eo]);
#pragma unroll
      for (int j = 0; j < 4; ++j)
        bf[j] = *reinterpret_cast<const bf16x8*>(&Bs[cur][(wacol + j * 16 + frow) * 64 + eo]);
#pragma unroll
      for (int i = 0; i < 2; ++i)
#pragma unroll
        for (int j = 0; j < 4; ++j)
          acc[i][j] = __builtin_amdgcn_mfma_f32_16x16x32_bf16(af[i], bf[j], acc[i][j], 0, 0, 0);
    }
    __builtin_amdgcn_sched_barrier(0);
    __builtin_amdgcn_s_barrier();
    __builtin_amdgcn_sched_barrier(0);
    cur ^= 1;
  }

#pragma unroll
  for (int i = 0; i < 2; ++i) {
#pragma unroll
    for (int jj = 0; jj < 4; ++jj) {
      int r = mt * 64 + warow + i * 16 + (lane >> 4) * 4 + jj;
      if (r < n_e) {
        int tk = tok_list[row0 + r];
        float gt = gate_lst[row0 + r];
        float* yrow = out + (size_t)tk * DIM;
#pragma unroll
        for (int j = 0; j < 4; ++j) {
          int d = nt * 128 + wacol + j * 16 + (lane & 15);
          atomicAdd(&yrow[d], gt * acc[i][j][jj]);
        }
      }
    }
  }
}

extern "C" void kernel_launch(void* const* d_in, const int* in_sizes, int n_in,
                              void* d_out, int out_size, void* d_ws, size_t ws_size,
                              hipStream_t stream) {
  const float* x = (const float*)d_in[0];
  const float* wr = (const float*)d_in[1];
  const float* wg = (const float*)d_in[2];
  const float* wu = (const float*)d_in[3];
  const float* wd = (const float*)d_in[4];
  float* out = (float*)d_out;

  char* ws = (char*)d_ws;
  size_t off = 0;
  auto alloc = [&](size_t bytes) {
    char* p = ws + off;
    off += (bytes + 255) & ~(size_t)255;
    return p;
  };
  unsigned short* xb   = (unsigned short*)alloc((size_t)T_TOK * DIM * 2);
  unsigned short* wgb  = (unsigned short*)alloc((size_t)NE * FFN * DIM * 2);
  unsigned short* wub  = (unsigned short*)alloc((size_t)NE * FFN * DIM * 2);
  unsigned short* wdb  = (unsigned short*)alloc((size_t)NE * DIM * FFN * 2);
  unsigned short* hbuf = (unsigned short*)alloc((size_t)T_TOK * 2 * FFN * 2);
  int* top_i     = (int*)alloc(T_TOK * 2 * 4);
  float* top_g   = (float*)alloc(T_TOK * 2 * 4);
  int* tok_list  = (int*)alloc(T_TOK * 2 * 4);
  float* gate_lst = (float*)alloc(T_TOK * 2 * 4);
  int* offs      = (int*)alloc(64);
  int* cursor    = (int*)alloc(64);
  if (off > ws_size) return;

  prep<<<6912, 256, 0, stream>>>(x, wr, wg, wu, wd, xb, wgb, wub, wdb,
                                 top_i, top_g, (float4*)out);
  count_offsets<<<1, 256, 0, stream>>>(top_i, offs, cursor);
  scatter_tokens<<<(T_TOK + 255) / 256, 256, 0, stream>>>(top_i, top_g, cursor, tok_list,
                                                          gate_lst);
  gateup_gemm<<<dim3(FFN / 64, 32, NE), 256, 0, stream>>>(xb, wgb, wub, tok_list, offs, hbuf);
  down_gemm<<<dim3(DIM / 128, 32, NE), 256, 0, stream>>>(hbuf, wdb, tok_list, gate_lst,
                                                         offs, out);
}

// Round 14
// 181.320 us; speedup vs baseline: 1.1556x; 1.0625x over previous
//
#include <hip/hip_runtime.h>
#include <hip/hip_bf16.h>

// Problem dims (fixed by reference): B=2,S=1024 -> T=2048 tokens
#define T_TOK 2048
#define DIM   2048   // D
#define FFN   1024   // F
#define NE    8      // experts
// top_k = 2 hardcoded

typedef __attribute__((ext_vector_type(8))) short bf16x8;
typedef __attribute__((ext_vector_type(4))) float f32x4;

__device__ __forceinline__ unsigned short f2bf(float f) {
  __hip_bfloat16 h = __float2bfloat16(f);
  return __builtin_bit_cast(unsigned short, h);
}

__device__ __forceinline__ void gload_lds16(const unsigned short* g, unsigned short* l) {
  __builtin_amdgcn_global_load_lds(
      (const __attribute__((address_space(1))) void*)g,
      (__attribute__((address_space(3))) void*)l, 16, 0, 0);
}

// ============ fused preprocessing: cvt_w (nt) + router(+cvt x, nt) + zero_out ============
__global__ __launch_bounds__(256) void prep(
    const float* __restrict__ x, const float* __restrict__ wr,
    const float* __restrict__ wg, const float* __restrict__ wu, const float* __restrict__ wd,
    unsigned short* __restrict__ xb, unsigned short* __restrict__ wgb,
    unsigned short* __restrict__ wub, unsigned short* __restrict__ wdb,
    int* __restrict__ top_i, float* __restrict__ top_g, float4* __restrict__ outz) {
  const int bid = blockIdx.x;
  if (bid < 6144) {
    int b = bid;
    const float* src; unsigned short* dst;
    if (b < 2048)       { src = wg; dst = wgb; }
    else if (b < 4096)  { src = wu; dst = wub; b -= 2048; }
    else                { src = wd; dst = wdb; b -= 4096; }
    const f32x4* s = reinterpret_cast<const f32x4*>(src) + (long)b * 2048 + threadIdx.x;
    ushort4* d = reinterpret_cast<ushort4*>(dst) + (long)b * 2048 + threadIdx.x;
    f32x4 v[8];
#pragma unroll
    for (int g = 0; g < 8; ++g) v[g] = __builtin_nontemporal_load(&s[g * 256]);
#pragma unroll
    for (int g = 0; g < 8; ++g) {
      ushort4 o;
      o.x = f2bf(v[g][0]); o.y = f2bf(v[g][1]); o.z = f2bf(v[g][2]); o.w = f2bf(v[g][3]);
      d[g * 256] = o;
    }
    return;
  }
  if (bid < 6656) {
    int t = (bid - 6144) * 4 + (threadIdx.x >> 6);
    int lane = threadIdx.x & 63;
    const f32x4* xr = reinterpret_cast<const f32x4*>(x) + (size_t)t * (DIM / 4);
    const float4* wrv = reinterpret_cast<const float4*>(wr);
    ushort4* xbr = reinterpret_cast<ushort4*>(xb + (size_t)t * DIM);
    float acc[NE];
#pragma unroll
    for (int e = 0; e < NE; ++e) acc[e] = 0.f;
#pragma unroll
    for (int it = 0; it < DIM / 4 / 64; ++it) {
      int d4 = it * 64 + lane;
      f32x4 xv = __builtin_nontemporal_load(&xr[d4]);
      ushort4 o;
      o.x = f2bf(xv[0]); o.y = f2bf(xv[1]); o.z = f2bf(xv[2]); o.w = f2bf(xv[3]);
      xbr[d4] = o;
#pragma unroll
      for (int e = 0; e < NE; ++e) {
        float4 wv = wrv[e * (DIM / 4) + d4];
        acc[e] += xv[0] * wv.x + xv[1] * wv.y + xv[2] * wv.z + xv[3] * wv.w;
      }
    }
#pragma unroll
    for (int off = 32; off > 0; off >>= 1) {
#pragma unroll
      for (int e = 0; e < NE; ++e) acc[e] += __shfl_xor(acc[e], off, 64);
    }
    if (lane == 0) {
      int i0 = 0; float m0 = acc[0];
#pragma unroll
      for (int e = 1; e < NE; ++e) if (acc[e] > m0) { m0 = acc[e]; i0 = e; }
      int i1 = -1; float m1 = -3.4e38f;
#pragma unroll
      for (int e = 0; e < NE; ++e) if (e != i0 && acc[e] > m1) { m1 = acc[e]; i1 = e; }
      float tv = expf(m1 - m0);
      float den = 1.f + tv;
      top_i[t * 2 + 0] = i0; top_i[t * 2 + 1] = i1;
      top_g[t * 2 + 0] = 1.f / den; top_g[t * 2 + 1] = tv / den;
    }
    return;
  }
  // zero d_out: 256 blocks cover 2^20 float4
  int i = (bid - 6656) * 256 + threadIdx.x;
  float4 z = {0.f, 0.f, 0.f, 0.f};
  for (; i < T_TOK * DIM / 4; i += 256 * 256) outz[i] = z;
}

// ---------------- routing: count + prefix + scatter, one block ----------------
// Row placement order is scheduler-dependent but output values are placement-
// invariant (each compact row computed independently; 2 commutative adds/elem).
__global__ __launch_bounds__(256) void route_tokens(
    const int* __restrict__ top_i, const float* __restrict__ top_g,
    int* __restrict__ offs, int* __restrict__ tok_list, float* __restrict__ gate_lst) {
  __shared__ int cnt[NE];
  __shared__ int cur[NE];
  if (threadIdx.x < NE) cnt[threadIdx.x] = 0;
  __syncthreads();
  for (int i = threadIdx.x; i < T_TOK * 2; i += 256) atomicAdd(&cnt[top_i[i]], 1);
  __syncthreads();
  if (threadIdx.x == 0) {
    int s = 0;
    for (int e = 0; e < NE; ++e) { offs[e] = s; cur[e] = s; s += cnt[e]; }
    offs[NE] = s;
  }
  __syncthreads();
  for (int t = threadIdx.x; t < T_TOK; t += 256) {
#pragma unroll
    for (int s = 0; s < 2; ++s) {
      int e = top_i[t * 2 + s];
      int p = atomicAdd(&cur[e], 1);
      tok_list[p] = t;
      gate_lst[p] = top_g[t * 2 + s];
    }
  }
}

// ============ fused gate+up grouped GEMM: BM=64, BN=64, BK=64, T4+T5 ============
// Per iter: stage(next, 6 loads/wave) -> vmcnt(6) -> barrier -> setprio(1) MFMA
// setprio(0) -> barrier. Counted vmcnt keeps next tile in flight across the iter.
__global__ __launch_bounds__(256, 3) void gateup_gemm(
    const unsigned short* __restrict__ xb, const unsigned short* __restrict__ wgb,
    const unsigned short* __restrict__ wub, const int* __restrict__ tok_list,
    const int* __restrict__ offs, unsigned short* __restrict__ hbuf) {
  const int e = blockIdx.z;
  const int row0 = offs[e];
  const int n_e = offs[e + 1] - row0;
  const int mt = blockIdx.y;
  if (mt * 64 >= n_e) return;
  const int nt = blockIdx.x;    // F tile of 64

  __shared__ unsigned short As[2][64 * 64];   // 2 x 8KB
  __shared__ unsigned short Bg[2][64 * 64];   // 2 x 8KB
  __shared__ unsigned short Bu[2][64 * 64];   // 2 x 8KB

  const int tid = threadIdx.x;
  const int wid = tid >> 6;
  const int lane = tid & 63;

  const int gchunk = (((lane & 7) ^ ((lane >> 3) & 7)) << 3);

  const unsigned short* gA[2];
  int lAoff[2];
#pragma unroll
  for (int p = 0; p < 2; ++p) {
    int rt = wid * 16 + p * 8 + (lane >> 3);
    int ar = mt * 64 + rt; if (ar >= n_e) ar = n_e - 1;
    gA[p] = xb + (size_t)tok_list[row0 + ar] * DIM + gchunk;
    lAoff[p] = (wid * 16 + p * 8) * 64;
  }
  const size_t wbase = (size_t)e * FFN * DIM + (size_t)(nt * 64) * DIM;
  const unsigned short* gG[2];
  const unsigned short* gU[2];
  int lBoff[2];
#pragma unroll
  for (int p = 0; p < 2; ++p) {
    int rt = wid * 16 + p * 8 + (lane >> 3);
    gG[p] = wgb + wbase + (size_t)rt * DIM + gchunk;
    gU[p] = wub + wbase + (size_t)rt * DIM + gchunk;
    lBoff[p] = (wid * 16 + p * 8) * 64;
  }

  auto stage = [&](int buf, int k0) {   // 6 gload_lds per wave
#pragma unroll
    for (int p = 0; p < 2; ++p) {
      gload_lds16(gA[p] + k0, &As[buf][lAoff[p]]);
      gload_lds16(gG[p] + k0, &Bg[buf][lBoff[p]]);
      gload_lds16(gU[p] + k0, &Bu[buf][lBoff[p]]);
    }
  };

  f32x4 accg[2][2];
  f32x4 accu[2][2];
#pragma unroll
  for (int i = 0; i < 2; ++i)
#pragma unroll
    for (int j = 0; j < 2; ++j) {
      accg[i][j] = (f32x4){0.f, 0.f, 0.f, 0.f};
      accu[i][j] = (f32x4){0.f, 0.f, 0.f, 0.f};
    }

  const int warow = (wid >> 1) * 32;   // 2x2 wave grid, 32x32 per wave
  const int wacol = (wid & 1) * 32;
  const int frow = lane & 15;
  const int eo0 = ((((lane >> 4)) ^ (lane & 7)) << 3);
  const int eo1 = (((4 + (lane >> 4)) ^ (lane & 7)) << 3);

  stage(0, 0);

  const int NT = DIM / 64;
  int cur = 0;
  for (int t = 0; t < NT; ++t) {
    if (t + 1 < NT) {
      stage(cur ^ 1, (t + 1) * 64);
      asm volatile("s_waitcnt vmcnt(6)" ::: "memory");
    } else {
      asm volatile("s_waitcnt vmcnt(0)" ::: "memory");
    }
    __builtin_amdgcn_sched_barrier(0);
    __builtin_amdgcn_s_barrier();
    __builtin_amdgcn_sched_barrier(0);
#pragma unroll
    for (int kk = 0; kk < 2; ++kk) {
      const int eo = kk ? eo1 : eo0;
      bf16x8 af[2], bg[2], bu[2];
#pragma unroll
      for (int i = 0; i < 2; ++i)
        af[i] = *reinterpret_cast<const bf16x8*>(&As[cur][(warow + i * 16 + frow) * 64 + eo]);
#pragma unroll
      for (int j = 0; j < 2; ++j) {
        bg[j] = *reinterpret_cast<const bf16x8*>(&Bg[cur][(wacol + j * 16 + frow) * 64 + eo]);
        bu[j] = *reinterpret_cast<const bf16x8*>(&Bu[cur][(wacol + j * 16 + frow) * 64 + eo]);
      }
      __builtin_amdgcn_s_setprio(1);
#pragma unroll
      for (int i = 0; i < 2; ++i)
#pragma unroll
        for (int j = 0; j < 2; ++j) {
          accg[i][j] = __builtin_amdgcn_mfma_f32_16x16x32_bf16(af[i], bg[j], accg[i][j], 0, 0, 0);
          accu[i][j] = __builtin_amdgcn_mfma_f32_16x16x32_bf16(af[i], bu[j], accu[i][j], 0, 0, 0);
        }
      __builtin_amdgcn_s_setprio(0);
    }
    __builtin_amdgcn_sched_barrier(0);
    __builtin_amdgcn_s_barrier();
    __builtin_amdgcn_sched_barrier(0);
    cur ^= 1;
  }

  // epilogue: h = silu(g)*u -> bf16
#pragma unroll
  for (int i = 0; i < 2; ++i) {
#pragma unroll
    for (int jj = 0; jj < 4; ++jj) {
      int r = mt * 64 + warow + i * 16 + (lane >> 4) * 4 + jj;
      if (r < n_e) {
#pragma unroll
        for (int j = 0; j < 2; ++j) {
          float g = accg[i][j][jj];
          float u = accu[i][j][jj];
          float h = (g / (1.f + __expf(-g))) * u;
          int f = nt * 64 + wacol + j * 16 + (lane & 15);
          hbuf[(size_t)(row0 + r) * FFN + f] = f2bf(h);
        }
      }
    }
  }
}

// ============ grouped down GEMM: BM=64, BN=128, BK=64, T4+T5 ============
// Epilogue: atomicAdd into out (exactly 2 commutative fp32 adds/element -> deterministic).
__global__ __launch_bounds__(256, 3) void down_gemm(
    const unsigned short* __restrict__ hbuf, const unsigned short* __restrict__ wdb,
    const int* __restrict__ tok_list, const float* __restrict__ gate_lst,
    const int* __restrict__ offs, float* __restrict__ out) {
  const int e = blockIdx.z;
  const int row0 = offs[e];
  const int n_e = offs[e + 1] - row0;
  const int mt = blockIdx.y;
  if (mt * 64 >= n_e) return;
  const int nt = blockIdx.x;  // D tile

  __shared__ unsigned short As[2][64 * 64];    // 2 x 8KB
  __shared__ unsigned short Bs[2][128 * 64];   // 2 x 16KB

  const int tid = threadIdx.x;
  const int wid = tid >> 6;
  const int lane = tid & 63;

  const int gchunk = (((lane & 7) ^ ((lane >> 3) & 7)) << 3);

  const unsigned short* gA[2];
  int lAoff[2];
#pragma unroll
  for (int p = 0; p < 2; ++p) {
    int rt = wid * 16 + p * 8 + (lane >> 3);
    int ar = mt * 64 + rt; if (ar >= n_e) ar = n_e - 1;
    gA[p] = hbuf + (size_t)(row0 + ar) * FFN + gchunk;
    lAoff[p] = (wid * 16 + p * 8) * 64;
  }
  const unsigned short* gB[4];
  int lBoff[4];
#pragma unroll
  for (int p = 0; p < 4; ++p) {
    int rt = wid * 32 + p * 8 + (lane >> 3);
    gB[p] = wdb + ((size_t)e * DIM + nt * 128 + rt) * FFN + gchunk;
    lBoff[p] = (wid * 32 + p * 8) * 64;
  }

  auto stage = [&](int buf, int k0) {   // 6 gload_lds per wave
#pragma unroll
    for (int p = 0; p < 2; ++p) gload_lds16(gA[p] + k0, &As[buf][lAoff[p]]);
#pragma unroll
    for (int p = 0; p < 4; ++p) gload_lds16(gB[p] + k0, &Bs[buf][lBoff[p]]);
  };

  f32x4 acc[2][4];
#pragma unroll
  for (int i = 0; i < 2; ++i)
#pragma unroll
    for (int j = 0; j < 4; ++j) acc[i][j] = (f32x4){0.f, 0.f, 0.f, 0.f};

  const int warow = (wid >> 1) * 32;
  const int wacol = (wid & 1) * 64;
  const int frow = lane & 15;
  const int eo0 = ((((lane >> 4)) ^ (lane & 7)) << 3);
  const int eo1 = (((4 + (lane >> 4)) ^ (lane & 7)) << 3);

  stage(0, 0);

  const int NT = FFN / 64;
  int cur = 0;
  for (int t = 0; t < NT; ++t) {
    if (t + 1 < NT) {
      stage(cur ^ 1, (t + 1) * 64);
      asm volatile("s_waitcnt vmcnt(6)" ::: "memory");
    } else {
      asm volatile("s_waitcnt vmcnt(0)" ::: "memory");
    }
    __builtin_amdgcn_sched_barrier(0);
    __builtin_amdgcn_s_barrier();
    __builtin_amdgcn_sched_barrier(0);
#pragma unroll
    for (int kk = 0; kk < 2; ++kk) {
      const int eo = kk ? eo1 : eo0;
      bf16x8 af[2], bf[4];
#pragma unroll
      for (int i = 0; i < 2; ++i)
        af[i] = *reinterpret_cast<const bf16x8*>(&As[cur][(warow + i * 16 + frow) * 64 + eo]);
#pragma unroll
      for (int j = 0; j < 4; ++j)
        bf[j] = *reinterpret_cast<const bf16x8*>(&Bs[cur][(wacol + j * 16 + frow) * 64 + eo]);
      __builtin_amdgcn_s_setprio(1);
#pragma unroll
      for (int i = 0; i < 2; ++i)
#pragma unroll
        for (int j = 0; j < 4; ++j)
          acc[i][j] = __builtin_amdgcn_mfma_f32_16x16x32_bf16(af[i], bf[j], acc[i][j], 0, 0, 0);
      __builtin_amdgcn_s_setprio(0);
    }
    __builtin_amdgcn_sched_barrier(0);
    __builtin_amdgcn_s_barrier();
    __builtin_amdgcn_sched_barrier(0);
    cur ^= 1;
  }

#pragma unroll
  for (int i = 0; i < 2; ++i) {
#pragma unroll
    for (int jj = 0; jj < 4; ++jj) {
      int r = mt * 64 + warow + i * 16 + (lane >> 4) * 4 + jj;
      if (r < n_e) {
        int tk = tok_list[row0 + r];
        float gt = gate_lst[row0 + r];
        float* yrow = out + (size_t)tk * DIM;
#pragma unroll
        for (int j = 0; j < 4; ++j) {
          int d = nt * 128 + wacol + j * 16 + (lane & 15);
          atomicAdd(&yrow[d], gt * acc[i][j][jj]);
        }
      }
    }
  }
}

extern "C" void kernel_launch(void* const* d_in, const int* in_sizes, int n_in,
                              void* d_out, int out_size, void* d_ws, size_t ws_size,
                              hipStream_t stream) {
  const float* x = (const float*)d_in[0];
  const float* wr = (const float*)d_in[1];
  const float* wg = (const float*)d_in[2];
  const float* wu = (const float*)d_in[3];
  const float* wd = (const float*)d_in[4];
  float* out = (float*)d_out;

  char* ws = (char*)d_ws;
  size_t off = 0;
  auto alloc = [&](size_t bytes) {
    char* p = ws + off;
    off += (bytes + 255) & ~(size_t)255;
    return p;
  };
  unsigned short* xb   = (unsigned short*)alloc((size_t)T_TOK * DIM * 2);
  unsigned short* wgb  = (unsigned short*)alloc((size_t)NE * FFN * DIM * 2);
  unsigned short* wub  = (unsigned short*)alloc((size_t)NE * FFN * DIM * 2);
  unsigned short* wdb  = (unsigned short*)alloc((size_t)NE * DIM * FFN * 2);
  unsigned short* hbuf = (unsigned short*)alloc((size_t)T_TOK * 2 * FFN * 2);
  int* top_i     = (int*)alloc(T_TOK * 2 * 4);
  float* top_g   = (float*)alloc(T_TOK * 2 * 4);
  int* tok_list  = (int*)alloc(T_TOK * 2 * 4);
  float* gate_lst = (float*)alloc(T_TOK * 2 * 4);
  int* offs      = (int*)alloc(64);
  if (off > ws_size) return;

  prep<<<6912, 256, 0, stream>>>(x, wr, wg, wu, wd, xb, wgb, wub, wdb,
                                 top_i, top_g, (float4*)out);
  route_tokens<<<1, 256, 0, stream>>>(top_i, top_g, offs, tok_list, gate_lst);
  gateup_gemm<<<dim3(FFN / 64, 32, NE), 256, 0, stream>>>(xb, wgb, wub, tok_list, offs, hbuf);
  down_gemm<<<dim3(DIM / 128, 32, NE), 256, 0, stream>>>(hbuf, wdb, tok_list, gate_lst,
                                                         offs, out);
}